// Round 5
// baseline (212.731 us; speedup 1.0000x reference)
//
#include <hip/hip_runtime.h>
#include <hip/hip_bf16.h>
#include <math.h>

typedef short short8 __attribute__((ext_vector_type(8)));
typedef short short4v __attribute__((ext_vector_type(4)));
typedef float f32x4 __attribute__((ext_vector_type(4)));

__device__ __forceinline__ short f2bf(float f) {
  union { float f; unsigned u; } v; v.f = f;
  unsigned r = v.u + 0x7FFFu + ((v.u >> 16) & 1u);
  return (short)(r >> 16);
}
__device__ __forceinline__ float bf2f(short s) {
  union { unsigned u; float f; } v; v.u = ((unsigned)(unsigned short)s) << 16;
  return v.f;
}

// -------- generic f32 -> bf16 cast, 4 elems/thread -----------------------
__global__ __launch_bounds__(256) void cast_kernel(const float* __restrict__ in,
                                                   short* __restrict__ out, int n4) {
  int i = blockIdx.x * blockDim.x + threadIdx.x;
  if (i < n4) {
    float4 v = ((const float4*)in)[i];
    short4v o;
    o.x = f2bf(v.x); o.y = f2bf(v.y); o.z = f2bf(v.z); o.w = f2bf(v.w);
    ((short4v*)out)[i] = o;
  }
}

// -------- DCT matrix: D[k][n] = 2*cos(pi/(2N) * k * (2n+1)), N=1024 -------
__global__ __launch_bounds__(256) void build_D(short* __restrict__ D) {
  int t = blockIdx.x * 256 + threadIdx.x;
  int k = t >> 10, n = t & 1023;
  const float s = 1.5339807878856412e-03f;  // pi/2048
  float arg = (s * (float)k) * (float)(2 * n + 1);
  D[t] = f2bf(2.0f * cosf(arg));
}

// -------- fold 4 row-block partials -> per-(b,c) mu, rstd -----------------
__global__ __launch_bounds__(256) void ln_stats(const float2* __restrict__ partial,
                                                float2* __restrict__ musd) {
  int n = blockIdx.x * 256 + threadIdx.x;   // 16384
  float S = 0.f, Q = 0.f;
#pragma unroll
  for (int r = 0; r < 4; ++r) {
    float2 p = partial[(size_t)r * 16384 + n];
    S += p.x; Q += p.y;
  }
  float mu  = S * (1.f / 1024.f);
  float var = Q * (1.f / 1024.f) - mu * mu;   // biased, like nn.LayerNorm
  float2 o; o.x = mu; o.y = rsqrtf(var + 1e-6f);
  musd[n] = o;
}

// -------- streaming LN apply: freqT[b][k][c] in place, short8/thread ------
__global__ __launch_bounds__(256) void ln_apply(short* __restrict__ freqT,
                                                const float2* __restrict__ musd,
                                                const float* __restrict__ lnw,
                                                const float* __restrict__ lnb) {
  int t = blockIdx.x * 256 + threadIdx.x;
  int c8 = t & 63;
  int k  = (t >> 6) & 1023;
  int b  = t >> 16;
  size_t idx = ((size_t)b << 19) + (size_t)k * 512 + (size_t)c8 * 8;
  short8 v = *(const short8*)&freqT[idx];
  float w  = lnw[k];
  float bb = lnb[k];
  const float2* ms = &musd[b * 512 + c8 * 8];
  short8 o;
#pragma unroll
  for (int j = 0; j < 8; ++j) {
    float f = bf2f(v[j]);
    float2 m = ms[j];
    o[j] = f2bf((f - m.x) * m.y * w + bb);
  }
  *(short8*)&freqT[idx] = o;
}

// ======== 256x128 pipelined BT-GEMM: C[m,n] = sum_k A[m,k]*B[n,k] =========
// BK=64, 8 waves (2Mx4N), per-wave 128x32, acc[8][2] f32x4.
// A: 2-slot dbuf (32KB each); B: 4-slot ring (16KB each) -> 128KB LDS.
// 2 phases per K-tile (16 MFMA each); each phase stages ONE B quarter for
// tile kt+3 into the slot freed last iteration (fine interleave, m196/m201);
// A(kt+2) burst after the last phase barrier. Counted waits: vmcnt(6)/4/0.
// T2 swizzle: phys 16B slot = logical ^ (row&7), realized by inverse-
// permuting the GLOBAL source (LDS dest stays linear) + XOR on ds_read.
template<int EPI>
__global__ __launch_bounds__(512, 2) void gemm256(
    const short* __restrict__ A, const short* __restrict__ B,
    void* __restrict__ Cout, const short* __restrict__ XB,
    float2* __restrict__ P, int K, int NT, long strideA, long strideB)
{
  __shared__ short As[2][16384];
  __shared__ short Bs[4][8192];
  const int tid = threadIdx.x;
  const int l   = tid & 63;
  const int w   = tid >> 6;        // wave 0..7
  const int wm  = w >> 2;          // 0..1
  const int wn  = w & 3;           // 0..3
  const int l7  = l & 7;
  const int lr  = l & 15;
  const int lhi = l >> 4;

  // ---- T1 bijective XCD swizzle (grids divisible by 8) ----
  const int nwg = gridDim.x, q = nwg >> 3, orig = blockIdx.x;
  const int wgid = (orig & 7) * q + (orig >> 3);
  int bx, by, bz;
  if (EPI == 0)      { bx = wgid & 3; by = wgid >> 2;       bz = 0; }
  else if (EPI == 1) { bx = wgid & 3; by = (wgid >> 2) & 7; bz = wgid >> 5; }
  else               { bx = wgid & 1; by = (wgid >> 1) & 7; bz = wgid >> 4; }

  const long row0 = (long)bx * 256, col0 = (long)by * 128;
  const short* Ab = A + (size_t)bz * strideA + (size_t)row0 * K;
  const short* Bb = B + (size_t)bz * strideB + (size_t)col0 * K;

  // staging: thread -> row rowb = w*8 + (l>>3) in [0,64), 16B slot l&7;
  // global source column inverse-swizzled so LDS dest stays linear.
  const int rowb  = w * 8 + (l >> 3);
  const int colel = (l7 ^ (l >> 3)) * 8;
  // fragment reads: phys slot = logical ^ (row&7 = l7)
  const int arow  = (wm * 128 + lr) * 64;
  const int brow0 = (wn * 32 + lr) * 64;
  const int brow1 = brow0 + 1024;          // +16 rows
  const int sk0 = ((lhi    ) ^ l7) * 8;
  const int sk1 = ((lhi + 4) ^ l7) * 8;

  f32x4 acc[8][2];
#pragma unroll
  for (int i = 0; i < 8; ++i) { acc[i][0] = (f32x4){0,0,0,0}; acc[i][1] = (f32x4){0,0,0,0}; }

#define GLL(SRC, DST) __builtin_amdgcn_global_load_lds(                      \
      (const __attribute__((address_space(1))) void*)(SRC),                  \
      (__attribute__((address_space(3))) void*)(DST), 16, 0, 0)

#define STAGE_A(KT, D) do {                                                  \
    const size_t ko_ = (size_t)(KT) * 64 + colel;                            \
    _Pragma("unroll")                                                        \
    for (int r_ = 0; r_ < 4; ++r_)                                           \
      GLL(Ab + (size_t)(r_ * 64 + rowb) * K + ko_,                           \
          &As[D][r_ * 4096 + w * 512 + l * 8]);                              \
  } while (0)

#define STAGE_B_Q(KT, S, R) do {                                             \
    const size_t ko_ = (size_t)(KT) * 64 + colel;                            \
    GLL(Bb + (size_t)((R) * 64 + rowb) * K + ko_,                            \
        &Bs[S][(R) * 4096 + w * 512 + l * 8]);                               \
  } while (0)

  // prologue FIFO: B0(2), B1(2), A0(4), B2(2), A1(4)  -> 14 outstanding
  STAGE_B_Q(0, 0, 0); STAGE_B_Q(0, 0, 1);
  STAGE_B_Q(1, 1, 0); STAGE_B_Q(1, 1, 1);
  STAGE_A(0, 0);
  STAGE_B_Q(2, 2, 0); STAGE_B_Q(2, 2, 1);
  STAGE_A(1, 1);

#define MFMA(AV, BV, C) __builtin_amdgcn_mfma_f32_16x16x32_bf16(AV, BV, C, 0, 0, 0)

#define PH2(SK, SR)                                                          \
    a0 = *(const short8*)&Ad[arow + 0 * 1024 + (SK)];                        \
    a1 = *(const short8*)&Ad[arow + 1 * 1024 + (SK)];                        \
    a2 = *(const short8*)&Ad[arow + 2 * 1024 + (SK)];                        \
    a3 = *(const short8*)&Ad[arow + 3 * 1024 + (SK)];                        \
    a4 = *(const short8*)&Ad[arow + 4 * 1024 + (SK)];                        \
    a5 = *(const short8*)&Ad[arow + 5 * 1024 + (SK)];                        \
    a6 = *(const short8*)&Ad[arow + 6 * 1024 + (SK)];                        \
    a7 = *(const short8*)&Ad[arow + 7 * 1024 + (SK)];                        \
    b0 = *(const short8*)&Bd[brow0 + (SK)];                                  \
    b1 = *(const short8*)&Bd[brow1 + (SK)];                                  \
    if (doB) STAGE_B_Q(kt + 3, sB, SR);                                      \
    __builtin_amdgcn_s_barrier();                                            \
    asm volatile("s_waitcnt lgkmcnt(0)" ::: "memory");                       \
    __builtin_amdgcn_sched_barrier(0);                                       \
    __builtin_amdgcn_s_setprio(1);                                           \
    acc[0][0] = MFMA(a0, b0, acc[0][0]); acc[0][1] = MFMA(a0, b1, acc[0][1]); \
    acc[1][0] = MFMA(a1, b0, acc[1][0]); acc[1][1] = MFMA(a1, b1, acc[1][1]); \
    acc[2][0] = MFMA(a2, b0, acc[2][0]); acc[2][1] = MFMA(a2, b1, acc[2][1]); \
    acc[3][0] = MFMA(a3, b0, acc[3][0]); acc[3][1] = MFMA(a3, b1, acc[3][1]); \
    acc[4][0] = MFMA(a4, b0, acc[4][0]); acc[4][1] = MFMA(a4, b1, acc[4][1]); \
    acc[5][0] = MFMA(a5, b0, acc[5][0]); acc[5][1] = MFMA(a5, b1, acc[5][1]); \
    acc[6][0] = MFMA(a6, b0, acc[6][0]); acc[6][1] = MFMA(a6, b1, acc[6][1]); \
    acc[7][0] = MFMA(a7, b0, acc[7][0]); acc[7][1] = MFMA(a7, b1, acc[7][1]); \
    __builtin_amdgcn_s_setprio(0);                                           \
    __builtin_amdgcn_sched_barrier(0);                                       \
    __builtin_amdgcn_s_barrier();

  int cur = 0;
  for (int kt = 0; kt < NT; ++kt) {
    if (kt + 2 < NT)       { asm volatile("s_waitcnt vmcnt(6)" ::: "memory"); }
    else if (kt + 2 == NT) { asm volatile("s_waitcnt vmcnt(4)" ::: "memory"); }
    else                   { asm volatile("s_waitcnt vmcnt(0)" ::: "memory"); }
    __builtin_amdgcn_sched_barrier(0);
    __builtin_amdgcn_s_barrier();
    const short* Ad = As[cur];
    const short* Bd = Bs[kt & 3];
    const int sB = (kt + 3) & 3;
    const bool doB = (kt + 3) < NT;
    short8 a0, a1, a2, a3, a4, a5, a6, a7, b0, b1;

    PH2(sk0, 0)
    PH2(sk1, 1)

    if (kt + 2 < NT) STAGE_A(kt + 2, cur);
    cur ^= 1;
  }

  // ---------------- epilogue ----------------
  const int rb = (int)row0 + wm * 128 + lhi * 4;
  const int cb = (int)col0 + wn * 32 + lr;
  float sv[2], qv[2];
  sv[0] = sv[1] = qv[0] = qv[1] = 0.f;

#pragma unroll
  for (int mi = 0; mi < 8; ++mi) {
#pragma unroll
    for (int ni = 0; ni < 2; ++ni) {
#pragma unroll
      for (int j = 0; j < 4; ++j) {
        int r  = rb + mi * 16 + j;
        int cc = cb + ni * 16;
        float v = acc[mi][ni][j];
        if (EPI == 0) {
          sv[ni] += v; qv[ni] += v * v;
          ((short*)Cout)[((size_t)(cc >> 9) << 19) + (size_t)r * 512 + (cc & 511)] = f2bf(v);
        } else if (EPI == 1) {
          ((short*)Cout)[(size_t)bz * 1048576 + (size_t)r * 1024 + cc] = f2bf(v > 0.f ? v : 0.f);
        } else {
          size_t idx = (size_t)bz * 524288 + (size_t)r * 1024 + cc;
          float g = 1.f / (1.f + __expf(-v));
          ((float*)Cout)[idx] = bf2f(XB[idx]) * g;
        }
      }
    }
  }

  if (EPI == 0) {
    __syncthreads();
    float* redS = (float*)&As[0][0];       // [128 cols][8 contributors]
    float* redQ = redS + 1024;
    const int contrib = wm * 4 + lhi;
#pragma unroll
    for (int ni = 0; ni < 2; ++ni) {
      int ccl = wn * 32 + ni * 16 + lr;
      redS[ccl * 8 + contrib] = sv[ni];
      redQ[ccl * 8 + contrib] = qv[ni];
    }
    __syncthreads();
    if (tid < 128) {
      float S = 0.f, Q = 0.f;
#pragma unroll
      for (int i = 0; i < 8; ++i) { S += redS[tid * 8 + i]; Q += redQ[tid * 8 + i]; }
      float2 o; o.x = S; o.y = Q;
      P[(size_t)bx * 16384 + col0 + tid] = o;
    }
  }
#undef PH2
#undef MFMA
#undef STAGE_A
#undef STAGE_B_Q
#undef GLL
}

extern "C" void kernel_launch(void* const* d_in, const int* in_sizes, int n_in,
                              void* d_out, int out_size, void* d_ws, size_t ws_size,
                              hipStream_t stream) {
  const float* x    = (const float*)d_in[0];   // [32,512,1024]
  const float* w1   = (const float*)d_in[1];   // [1024,512]
  const float* w2   = (const float*)d_in[2];   // [512,1024]
  const float* ln_w = (const float*)d_in[3];   // [1024]
  const float* ln_b = (const float*)d_in[4];   // [1024]
  float* out = (float*)d_out;

  char* ws = (char*)d_ws;
  short* x_bf   = (short*)(ws);                  // 33,554,432 B
  short* D_bf   = (short*)(ws + 33554432);       //  2,097,152 B
  short* w1_bf  = (short*)(ws + 35651584);       //  1,048,576 B
  short* w2_bf  = (short*)(ws + 36700160);       //  1,048,576 B
  short* freqT  = (short*)(ws + 37748736);       // 33,554,432 B  [b][k][c]
  short* z1t    = (short*)(ws + 71303168);       // 67,108,864 B  [b][p][o]
  float2* part  = (float2*)(ws + 138412032);     //    524,288 B  [4][16384]
  float2* musd  = (float2*)(ws + 139460608);     //    131,072 B  [16384]

  cast_kernel<<<dim3(16384), dim3(256), 0, stream>>>(x,  x_bf,  16777216 / 4);
  cast_kernel<<<dim3(512),   dim3(256), 0, stream>>>(w1, w1_bf, 524288 / 4);
  cast_kernel<<<dim3(512),   dim3(256), 0, stream>>>(w2, w2_bf, 524288 / 4);
  build_D<<<dim3(4096), dim3(256), 0, stream>>>(D_bf);

  // GEMM1: C[k,(b,c)] = sum_n D[k,n] * x[(b,c),n] -> freqT + LN partials
  gemm256<0><<<dim3(512), dim3(512), 0, stream>>>(
      D_bf, x_bf, (void*)freqT, nullptr, part, 1024, 16, 0, 0);

  // LN stats: fold 4 row-block partials -> (mu, rstd) per (b,c)
  ln_stats<<<dim3(64), dim3(256), 0, stream>>>(part, musd);

  // LN apply: normalize freqT in place (streaming, vectorized)
  ln_apply<<<dim3(8192), dim3(256), 0, stream>>>(freqT, musd, ln_w, ln_b);

  // GEMM2: C[p,o] = sum_c Ht[b][p,c] * w1[o,c], relu -> z1t[b][p][o]
  gemm256<1><<<dim3(1024), dim3(512), 0, stream>>>(
      freqT, w1_bf, (void*)z1t, nullptr, nullptr, 512, 8, 524288, 0);

  // GEMM3: C[o2,p] = sum_j w2[o2,j] * z1t[b][p,j]; out = x_bf * sigmoid(C)
  gemm256<2><<<dim3(512), dim3(512), 0, stream>>>(
      w2_bf, z1t, (void*)out, x_bf, nullptr, 1024, 16, 0, 1048576);
}

// Round 6
// 166.501 us; speedup vs baseline: 1.2777x; 1.2777x over previous
//
#include <hip/hip_runtime.h>
#include <hip/hip_bf16.h>
#include <math.h>

typedef short short8 __attribute__((ext_vector_type(8)));
typedef short short4v __attribute__((ext_vector_type(4)));
typedef float f32x4 __attribute__((ext_vector_type(4)));

__device__ __forceinline__ short f2bf(float f) {
  union { float f; unsigned u; } v; v.f = f;
  unsigned r = v.u + 0x7FFFu + ((v.u >> 16) & 1u);
  return (short)(r >> 16);
}
__device__ __forceinline__ float bf2f(short s) {
  union { unsigned u; float f; } v; v.u = ((unsigned)(unsigned short)s) << 16;
  return v.f;
}

// -------- generic f32 -> bf16 cast, 4 elems/thread -----------------------
__global__ __launch_bounds__(256) void cast_kernel(const float* __restrict__ in,
                                                   short* __restrict__ out, int n4) {
  int i = blockIdx.x * blockDim.x + threadIdx.x;
  if (i < n4) {
    float4 v = ((const float4*)in)[i];
    short4v o;
    o.x = f2bf(v.x); o.y = f2bf(v.y); o.z = f2bf(v.z); o.w = f2bf(v.w);
    ((short4v*)out)[i] = o;
  }
}

// -------- DCT matrix: D[k][n] = 2*cos(pi/(2N) * k * (2n+1)), N=1024 -------
__global__ __launch_bounds__(256) void build_D(short* __restrict__ D) {
  int t = blockIdx.x * 256 + threadIdx.x;
  int k = t >> 10, n = t & 1023;
  const float s = 1.5339807878856412e-03f;  // pi/2048
  float arg = (s * (float)k) * (float)(2 * n + 1);
  D[t] = f2bf(2.0f * cosf(arg));
}

// -------- fold 4 row-block partials -> per-(b,c) mu, rstd -----------------
__global__ __launch_bounds__(256) void ln_stats(const float2* __restrict__ partial,
                                                float2* __restrict__ musd) {
  int n = blockIdx.x * 256 + threadIdx.x;   // 16384
  float S = 0.f, Q = 0.f;
#pragma unroll
  for (int r = 0; r < 4; ++r) {
    float2 p = partial[(size_t)r * 16384 + n];
    S += p.x; Q += p.y;
  }
  float mu  = S * (1.f / 1024.f);
  float var = Q * (1.f / 1024.f) - mu * mu;   // biased, like nn.LayerNorm
  float2 o; o.x = mu; o.y = rsqrtf(var + 1e-6f);
  musd[n] = o;
}

// -------- streaming LN apply: freqT[b][k][c] in place, short8/thread ------
__global__ __launch_bounds__(256) void ln_apply(short* __restrict__ freqT,
                                                const float2* __restrict__ musd,
                                                const float* __restrict__ lnw,
                                                const float* __restrict__ lnb) {
  int t = blockIdx.x * 256 + threadIdx.x;
  int c8 = t & 63;
  int k  = (t >> 6) & 1023;
  int b  = t >> 16;
  size_t idx = ((size_t)b << 19) + (size_t)k * 512 + (size_t)c8 * 8;
  short8 v = *(const short8*)&freqT[idx];
  float w  = lnw[k];
  float bb = lnb[k];
  const float2* ms = &musd[b * 512 + c8 * 8];
  short8 o;
#pragma unroll
  for (int j = 0; j < 8; ++j) {
    float f = bf2f(v[j]);
    float2 m = ms[j];
    o[j] = f2bf((f - m.x) * m.y * w + bb);
  }
  *(short8*)&freqT[idx] = o;
}

// ======== 256x256 pipelined BT-GEMM: C[m,n] = sum_k A[m,k]*B[n,k] =========
// BK=64, 8 waves (2Mx4N), per-wave 128x64, acc[8][4] f32x4, dbuf 128KB LDS.
// K-tile schedule (2 barriers total, counted lgkm gates, AITER-style):
//   vmcnt(8); bar1            -- tile kt staged
//   R1(4A k0 lo + 4B k0) R2(4A k0 hi)
//   lgkm(4)  Q1(16 MFMA)      -- R2+next reads drain under MFMA
//   R3(4A k1 lo + 4B k1)
//   lgkm(8)  Q2
//   R4(4A k1 hi)
//   lgkm(4)  Q3
//   lgkm(0); bar2             -- all reads of cur retired
//   STAGE(kt+2 -> cur)        -- overlaps Q4
//   Q4
// T2 swizzle: phys 16B slot = logical ^ (row&7); write side = inverse-
// permuted GLOBAL source (LDS dest linear); read side XORs the slot.
template<int EPI>
__global__ __launch_bounds__(512, 2) void gemm256(
    const short* __restrict__ A, const short* __restrict__ B,
    void* __restrict__ Cout, const short* __restrict__ XB,
    float2* __restrict__ P, int K, int NT, long strideA, long strideB)
{
  __shared__ short As[2][16384];
  __shared__ short Bs[2][16384];
  const int tid = threadIdx.x;
  const int l   = tid & 63;
  const int w   = tid >> 6;        // wave 0..7
  const int wm  = w >> 2;          // 0..1
  const int wn  = w & 3;           // 0..3
  const int l7  = l & 7;
  const int lr  = l & 15;
  const int lhi = l >> 4;

  // ---- T1 bijective XCD swizzle (grids divisible by 8) ----
  const int nwg = gridDim.x, q = nwg >> 3, orig = blockIdx.x;
  const int wgid = (orig & 7) * q + (orig >> 3);
  int bx, by, bz;
  if (EPI == 0)      { bx = wgid & 3; by = wgid >> 2;       bz = 0; }
  else if (EPI == 1) { bx = wgid & 3; by = (wgid >> 2) & 3; bz = wgid >> 4; }
  else               { by = wgid & 3; bx = (wgid >> 2) & 1; bz = wgid >> 3; }

  const long row0 = (long)bx * 256, col0 = (long)by * 256;
  const short* Ab = A + (size_t)bz * strideA + (size_t)row0 * K;
  const short* Bb = B + (size_t)bz * strideB + (size_t)col0 * K;

  // staging: thread -> row rowb = w*8 + (l>>3), 16B slot l&7; source column
  // inverse-swizzled so the linear LDS dest realizes the XOR layout.
  const int rowb  = w * 8 + (l >> 3);
  const int colel = (l7 ^ (l >> 3)) * 8;
  // fragment reads: phys slot = logical ^ (row&7 = l7)
  const int arow = (wm * 128 + lr) * 64;
  const int brow = (wn * 64  + lr) * 64;
  const int sk0 = ((lhi    ) ^ l7) * 8;
  const int sk1 = ((lhi + 4) ^ l7) * 8;

  f32x4 acc[8][4];
#pragma unroll
  for (int i = 0; i < 8; ++i)
#pragma unroll
    for (int j = 0; j < 4; ++j) acc[i][j] = (f32x4){0.f, 0.f, 0.f, 0.f};

#define GLL(SRC, DST) __builtin_amdgcn_global_load_lds(                      \
      (const __attribute__((address_space(1))) void*)(SRC),                  \
      (__attribute__((address_space(3))) void*)(DST), 16, 0, 0)

#define STAGE(KT, D) do {                                                    \
    const size_t ko_ = (size_t)(KT) * 64 + colel;                            \
    _Pragma("unroll")                                                        \
    for (int r_ = 0; r_ < 4; ++r_)                                           \
      GLL(Ab + (size_t)(r_ * 64 + rowb) * K + ko_,                           \
          &As[D][r_ * 4096 + w * 512 + l * 8]);                              \
    _Pragma("unroll")                                                        \
    for (int r_ = 0; r_ < 4; ++r_)                                           \
      GLL(Bb + (size_t)(r_ * 64 + rowb) * K + ko_,                           \
          &Bs[D][r_ * 4096 + w * 512 + l * 8]);                              \
  } while (0)

  STAGE(0, 0);
  STAGE(1, 1);

#define MFMA(AV, BV, C) __builtin_amdgcn_mfma_f32_16x16x32_bf16(AV, BV, C, 0, 0, 0)
#define QUAD(M0, V0, V1, V2, V3)                                             \
    __builtin_amdgcn_s_setprio(1);                                           \
    acc[M0+0][0] = MFMA(V0, b0, acc[M0+0][0]);                               \
    acc[M0+0][1] = MFMA(V0, b1, acc[M0+0][1]);                               \
    acc[M0+0][2] = MFMA(V0, b2, acc[M0+0][2]);                               \
    acc[M0+0][3] = MFMA(V0, b3, acc[M0+0][3]);                               \
    acc[M0+1][0] = MFMA(V1, b0, acc[M0+1][0]);                               \
    acc[M0+1][1] = MFMA(V1, b1, acc[M0+1][1]);                               \
    acc[M0+1][2] = MFMA(V1, b2, acc[M0+1][2]);                               \
    acc[M0+1][3] = MFMA(V1, b3, acc[M0+1][3]);                               \
    acc[M0+2][0] = MFMA(V2, b0, acc[M0+2][0]);                               \
    acc[M0+2][1] = MFMA(V2, b1, acc[M0+2][1]);                               \
    acc[M0+2][2] = MFMA(V2, b2, acc[M0+2][2]);                               \
    acc[M0+2][3] = MFMA(V2, b3, acc[M0+2][3]);                               \
    acc[M0+3][0] = MFMA(V3, b0, acc[M0+3][0]);                               \
    acc[M0+3][1] = MFMA(V3, b1, acc[M0+3][1]);                               \
    acc[M0+3][2] = MFMA(V3, b2, acc[M0+3][2]);                               \
    acc[M0+3][3] = MFMA(V3, b3, acc[M0+3][3]);                               \
    __builtin_amdgcn_s_setprio(0);                                           \
    __builtin_amdgcn_sched_barrier(0);

  int cur = 0;
  for (int kt = 0; kt < NT; ++kt) {
    if (kt + 2 < NT) { asm volatile("s_waitcnt vmcnt(8)" ::: "memory"); }
    else             { asm volatile("s_waitcnt vmcnt(0)" ::: "memory"); }
    __builtin_amdgcn_sched_barrier(0);
    __builtin_amdgcn_s_barrier();                    // bar1: kt staged
    const short* Ad = As[cur];
    const short* Bd = Bs[cur];
    short8 a0, a1, a2, a3, a4, a5, a6, a7;           // k0 then k1 A-frags
    short8 b0, b1, b2, b3;                           // current-k B-frags

    // R1: A k0 lo + B k0
    a0 = *(const short8*)&Ad[arow + 0 * 1024 + sk0];
    a1 = *(const short8*)&Ad[arow + 1 * 1024 + sk0];
    a2 = *(const short8*)&Ad[arow + 2 * 1024 + sk0];
    a3 = *(const short8*)&Ad[arow + 3 * 1024 + sk0];
    b0 = *(const short8*)&Bd[brow + 0 * 1024 + sk0];
    b1 = *(const short8*)&Bd[brow + 1 * 1024 + sk0];
    b2 = *(const short8*)&Bd[brow + 2 * 1024 + sk0];
    b3 = *(const short8*)&Bd[brow + 3 * 1024 + sk0];
    __builtin_amdgcn_sched_barrier(0);
    // R2: A k0 hi
    a4 = *(const short8*)&Ad[arow + 4 * 1024 + sk0];
    a5 = *(const short8*)&Ad[arow + 5 * 1024 + sk0];
    a6 = *(const short8*)&Ad[arow + 6 * 1024 + sk0];
    a7 = *(const short8*)&Ad[arow + 7 * 1024 + sk0];
    __builtin_amdgcn_sched_barrier(0);
    asm volatile("s_waitcnt lgkmcnt(4)" ::: "memory");   // R1 done
    __builtin_amdgcn_sched_barrier(0);
    QUAD(0, a0, a1, a2, a3)                               // Q1 (k0, m0-3)

    // R3: A k1 lo + B k1 (reuse a0-3 regs for k1; b loaded after Q2 uses)
    short8 c0, c1, c2, c3, c4, c5, c6, c7, e0, e1, e2, e3;
    c0 = *(const short8*)&Ad[arow + 0 * 1024 + sk1];
    c1 = *(const short8*)&Ad[arow + 1 * 1024 + sk1];
    c2 = *(const short8*)&Ad[arow + 2 * 1024 + sk1];
    c3 = *(const short8*)&Ad[arow + 3 * 1024 + sk1];
    e0 = *(const short8*)&Bd[brow + 0 * 1024 + sk1];
    e1 = *(const short8*)&Bd[brow + 1 * 1024 + sk1];
    e2 = *(const short8*)&Bd[brow + 2 * 1024 + sk1];
    e3 = *(const short8*)&Bd[brow + 3 * 1024 + sk1];
    __builtin_amdgcn_sched_barrier(0);
    asm volatile("s_waitcnt lgkmcnt(8)" ::: "memory");   // R2 done
    __builtin_amdgcn_sched_barrier(0);
    QUAD(4, a4, a5, a6, a7)                               // Q2 (k0, m4-7)

    // R4: A k1 hi
    c4 = *(const short8*)&Ad[arow + 4 * 1024 + sk1];
    c5 = *(const short8*)&Ad[arow + 5 * 1024 + sk1];
    c6 = *(const short8*)&Ad[arow + 6 * 1024 + sk1];
    c7 = *(const short8*)&Ad[arow + 7 * 1024 + sk1];
    __builtin_amdgcn_sched_barrier(0);
    asm volatile("s_waitcnt lgkmcnt(4)" ::: "memory");   // R3 done
    __builtin_amdgcn_sched_barrier(0);
    b0 = e0; b1 = e1; b2 = e2; b3 = e3;
    QUAD(0, c0, c1, c2, c3)                               // Q3 (k1, m0-3)

    asm volatile("s_waitcnt lgkmcnt(0)" ::: "memory");   // R4 done
    __builtin_amdgcn_sched_barrier(0);
    __builtin_amdgcn_s_barrier();                    // bar2: cur reads retired
    if (kt + 2 < NT) STAGE(kt + 2, cur);             // overlaps Q4
    __builtin_amdgcn_sched_barrier(0);
    QUAD(4, c4, c5, c6, c7)                               // Q4 (k1, m4-7)
    cur ^= 1;
  }

  // ---------------- epilogue ----------------
  const int rb = (int)row0 + wm * 128 + lhi * 4;
  const int cb = (int)col0 + wn * 64 + lr;
  float sv[4], qv[4];
#pragma unroll
  for (int ni = 0; ni < 4; ++ni) { sv[ni] = 0.f; qv[ni] = 0.f; }

#pragma unroll
  for (int mi = 0; mi < 8; ++mi) {
#pragma unroll
    for (int ni = 0; ni < 4; ++ni) {
#pragma unroll
      for (int j = 0; j < 4; ++j) {
        int r  = rb + mi * 16 + j;
        int cc = cb + ni * 16;
        float v = acc[mi][ni][j];
        if (EPI == 0) {
          sv[ni] += v; qv[ni] += v * v;
          ((short*)Cout)[((size_t)(cc >> 9) << 19) + (size_t)r * 512 + (cc & 511)] = f2bf(v);
        } else if (EPI == 1) {
          ((short*)Cout)[(size_t)bz * 1048576 + (size_t)r * 1024 + cc] = f2bf(v > 0.f ? v : 0.f);
        } else {
          size_t idx = (size_t)bz * 524288 + (size_t)r * 1024 + cc;
          float g = 1.f / (1.f + __expf(-v));
          ((float*)Cout)[idx] = bf2f(XB[idx]) * g;
        }
      }
    }
  }

  if (EPI == 0) {
    __syncthreads();
    float* redS = (float*)&As[0][0];       // [256 cols][8 contributors]
    float* redQ = redS + 2048;
    const int contrib = wm * 4 + lhi;
#pragma unroll
    for (int ni = 0; ni < 4; ++ni) {
      int ccl = wn * 64 + ni * 16 + lr;
      redS[ccl * 8 + contrib] = sv[ni];
      redQ[ccl * 8 + contrib] = qv[ni];
    }
    __syncthreads();
    if (tid < 256) {
      float S = 0.f, Q = 0.f;
#pragma unroll
      for (int i = 0; i < 8; ++i) { S += redS[tid * 8 + i]; Q += redQ[tid * 8 + i]; }
      float2 o; o.x = S; o.y = Q;
      P[(size_t)bx * 16384 + col0 + tid] = o;
    }
  }
#undef QUAD
#undef MFMA
#undef STAGE
#undef GLL
}

extern "C" void kernel_launch(void* const* d_in, const int* in_sizes, int n_in,
                              void* d_out, int out_size, void* d_ws, size_t ws_size,
                              hipStream_t stream) {
  const float* x    = (const float*)d_in[0];   // [32,512,1024]
  const float* w1   = (const float*)d_in[1];   // [1024,512]
  const float* w2   = (const float*)d_in[2];   // [512,1024]
  const float* ln_w = (const float*)d_in[3];   // [1024]
  const float* ln_b = (const float*)d_in[4];   // [1024]
  float* out = (float*)d_out;

  char* ws = (char*)d_ws;
  short* x_bf   = (short*)(ws);                  // 33,554,432 B
  short* D_bf   = (short*)(ws + 33554432);       //  2,097,152 B
  short* w1_bf  = (short*)(ws + 35651584);       //  1,048,576 B
  short* w2_bf  = (short*)(ws + 36700160);       //  1,048,576 B
  short* freqT  = (short*)(ws + 37748736);       // 33,554,432 B  [b][k][c]
  short* z1t    = (short*)(ws + 71303168);       // 67,108,864 B  [b][p][o]
  float2* part  = (float2*)(ws + 138412032);     //    524,288 B  [4][16384]
  float2* musd  = (float2*)(ws + 139460608);     //    131,072 B  [16384]

  cast_kernel<<<dim3(16384), dim3(256), 0, stream>>>(x,  x_bf,  16777216 / 4);
  cast_kernel<<<dim3(512),   dim3(256), 0, stream>>>(w1, w1_bf, 524288 / 4);
  cast_kernel<<<dim3(512),   dim3(256), 0, stream>>>(w2, w2_bf, 524288 / 4);
  build_D<<<dim3(4096), dim3(256), 0, stream>>>(D_bf);

  // GEMM1: C[k,(b,c)] = sum_n D[k,n] * x[(b,c),n] -> freqT + LN partials
  gemm256<0><<<dim3(256), dim3(512), 0, stream>>>(
      D_bf, x_bf, (void*)freqT, nullptr, part, 1024, 16, 0, 0);

  // LN stats: fold 4 row-block partials -> (mu, rstd) per (b,c)
  ln_stats<<<dim3(64), dim3(256), 0, stream>>>(part, musd);

  // LN apply: normalize freqT in place (streaming, vectorized)
  ln_apply<<<dim3(8192), dim3(256), 0, stream>>>(freqT, musd, ln_w, ln_b);

  // GEMM2: C[p,o] = sum_c Ht[b][p,c] * w1[o,c], relu -> z1t[b][p][o]
  gemm256<1><<<dim3(512), dim3(512), 0, stream>>>(
      freqT, w1_bf, (void*)z1t, nullptr, nullptr, 512, 8, 524288, 0);

  // GEMM3: C[o2,p] = sum_j w2[o2,j] * z1t[b][p,j]; out = x_bf * sigmoid(C)
  gemm256<2><<<dim3(256), dim3(512), 0, stream>>>(
      w2_bf, z1t, (void*)out, x_bf, nullptr, 1024, 16, 0, 1048576);
}